// Round 2
// 655.032 us; speedup vs baseline: 1.0506x; 1.0506x over previous
//
#include <hip/hip_runtime.h>

// SafenessLoss: K=8 streams, B=131072 samples, D=128, fp32.
// 512 MiB read exactly once -> ~86 us @ 6.3 TB/s floor for the main kernel.
// One half-wave (32 lanes) per sample-PAIR per iteration: lane h loads the
// float4 at byte offset 16*h of each 512 B row; samples b0,b0+1 are
// contiguous so each wave instruction covers a contiguous 1 KiB per stream
// and the pair-loop covers 2 KiB. 16 dwordx4 in flight per thread.
// Nontemporal loads: the 512 MiB stream is strictly single-use.
// No atomics: per-block partials to private ws slots, tiny final reduce.

#define NBLOCKS 2048

// clang native vector type: __builtin_nontemporal_load requires a vector of
// scalar types, NOT HIP's float4 class.
typedef float fx4 __attribute__((ext_vector_type(4)));

__global__ __launch_bounds__(256) void safeness_main(
    const float* __restrict__ emb, const int* __restrict__ target,
    int B, float* __restrict__ ws) {
  const int tid = threadIdx.x;
  const int h = tid & 31;                        // lane within half-wave
  const int sp = blockIdx.x * 8 + (tid >> 5);    // half-wave processor id
  const int P = NBLOCKS * 8;                     // 16384 processors
  const long long strideK = (long long)B * 128;

  float part_loss = 0.f, part_cnt = 0.f;

  // each half-wave handles samples {2sp, 2sp+1} + it*32768 -> 4 iterations
  for (int b0 = 2 * sp; b0 < B; b0 += 2 * P) {
    const float* base0 = emb + (long long)b0 * 128 + (h << 2);

    fx4 a0 = __builtin_nontemporal_load((const fx4*)base0);
    fx4 a1 = __builtin_nontemporal_load((const fx4*)(base0 + 128));
    fx4 e0[7], e1[7];
#pragma unroll
    for (int k = 0; k < 7; ++k) {
      const float* p = base0 + (long long)(k + 1) * strideK;
      e0[k] = __builtin_nontemporal_load((const fx4*)p);
      e1[k] = __builtin_nontemporal_load((const fx4*)(p + 128));
    }

    int2 t0 = *(const int2*)(target + b0);       // b0 even -> 8B aligned
    int2 tk[7];
#pragma unroll
    for (int k = 0; k < 7; ++k)
      tk[k] = *(const int2*)(target + (long long)(k + 1) * B + b0);

    float d0[7], d1[7];
#pragma unroll
    for (int k = 0; k < 7; ++k) {
      float dx = a0.x - e0[k].x, dy = a0.y - e0[k].y;
      float dz = a0.z - e0[k].z, dw = a0.w - e0[k].w;
      float s0 = dx * dx + dy * dy + dz * dz + dw * dw;
      dx = a1.x - e1[k].x; dy = a1.y - e1[k].y;
      dz = a1.z - e1[k].z; dw = a1.w - e1[k].w;
      float s1 = dx * dx + dy * dy + dz * dz + dw * dw;
      // butterfly within the 32-lane half (masks 1..16 stay in-half);
      // s0/s1 chains are independent -> scheduler interleaves them
#pragma unroll
      for (int m = 1; m <= 16; m <<= 1) {
        s0 += __shfl_xor(s0, m);
        s1 += __shfl_xor(s1, m);
      }
      d0[k] = s0;
      d1[k] = s1;
    }

    bool any0 = false, any1 = false;
    bool sm0[7], sm1[7];
    float ss0 = 0.f, ss1 = 0.f, mx0 = -INFINITY, mx1 = -INFINITY;
#pragma unroll
    for (int k = 0; k < 7; ++k) {
      sm0[k] = (tk[k].x == t0.x);
      sm1[k] = (tk[k].y == t0.y);
      if (sm0[k]) { any0 = true; ss0 += d0[k]; mx0 = fmaxf(mx0, d0[k]); }
      if (sm1[k]) { any1 = true; ss1 += d1[k]; mx1 = fmaxf(mx1, d1[k]); }
    }
    float al0 = any0 ? mx0 : 1.0f;
    float al1 = any1 ? mx1 : 1.0f;

    float ns0 = 0.f, ns1 = 0.f;
    bool an0 = false, an1 = false;
#pragma unroll
    for (int k = 0; k < 7; ++k) {
      float m0 = d0[k] - al0, m1 = d1[k] - al1;
      if (!sm0[k] && m0 < 0.f) { ns0 += m0; an0 = true; }
      if (!sm1[k] && m1 < 0.f) { ns1 += m1; an1 = true; }
    }
    if (h == 0) {
      if (any0 || an0) { part_loss += ss0 - ns0; part_cnt += 1.f; }
      if (any1 || an1) { part_loss += ss1 - ns1; part_cnt += 1.f; }
    }
  }

  // full-wave butterfly (only lanes 0 and 32 hold nonzero)
#pragma unroll
  for (int m = 1; m <= 32; m <<= 1) {
    part_loss += __shfl_xor(part_loss, m);
    part_cnt += __shfl_xor(part_cnt, m);
  }

  __shared__ float s_loss[4], s_cnt[4];
  const int wave = tid >> 6;
  if ((tid & 63) == 0) { s_loss[wave] = part_loss; s_cnt[wave] = part_cnt; }
  __syncthreads();
  if (tid == 0) {
    // private slot per block -- no atomics, no memset needed
    ws[2 * blockIdx.x]     = s_loss[0] + s_loss[1] + s_loss[2] + s_loss[3];
    ws[2 * blockIdx.x + 1] = s_cnt[0] + s_cnt[1] + s_cnt[2] + s_cnt[3];
  }
}

__global__ __launch_bounds__(256) void safeness_final(
    const float* __restrict__ ws, float* __restrict__ out) {
  const int tid = threadIdx.x;
  float L = 0.f, C = 0.f;
  for (int i = tid; i < NBLOCKS; i += 256) {
    L += ws[2 * i];
    C += ws[2 * i + 1];
  }
#pragma unroll
  for (int m = 1; m <= 32; m <<= 1) {
    L += __shfl_xor(L, m);
    C += __shfl_xor(C, m);
  }
  __shared__ float s_loss[4], s_cnt[4];
  const int wave = tid >> 6;
  if ((tid & 63) == 0) { s_loss[wave] = L; s_cnt[wave] = C; }
  __syncthreads();
  if (tid == 0) {
    float Lt = s_loss[0] + s_loss[1] + s_loss[2] + s_loss[3];
    float Ct = s_cnt[0] + s_cnt[1] + s_cnt[2] + s_cnt[3];
    out[0] = Lt / fmaxf(Ct, 1.0f);
  }
}

extern "C" void kernel_launch(void* const* d_in, const int* in_sizes, int n_in,
                              void* d_out, int out_size, void* d_ws, size_t ws_size,
                              hipStream_t stream) {
  const float* emb = (const float*)d_in[0];
  const int* target = (const int*)d_in[1];
  const int B = in_sizes[1] / 8;   // target is [K=8, B]
  float* ws = (float*)d_ws;

  safeness_main<<<NBLOCKS, 256, 0, stream>>>(emb, target, B, ws);
  safeness_final<<<1, 256, 0, stream>>>(ws, (float*)d_out);
}